// Round 1
// baseline (589.409 us; speedup 1.0000x reference)
//
#include <hip/hip_runtime.h>
#include <math.h>

#define EMB 256
#define MID 256
#define OUTF 128

__device__ __forceinline__ float gelu_exact(float x) {
    return 0.5f * x * (1.0f + erff(x * 0.70710678118654752f));
}

// ---------------- graph build ----------------

__global__ void deg_kernel(const int* __restrict__ dst, int* __restrict__ deg, int E) {
    int e = blockIdx.x * blockDim.x + threadIdx.x;
    if (e < E) atomicAdd(&deg[dst[e]], 1);
}

__global__ void dis_kernel(const int* __restrict__ deg, float* __restrict__ dis, int n) {
    int i = blockIdx.x * blockDim.x + threadIdx.x;
    if (i < n) dis[i] = rsqrtf((float)(deg[i] + 1));  // +1: self loop
}

// exclusive scan of deg -> row_start (and cursor copy); single block of 1024
__global__ void scan_kernel(const int* __restrict__ deg, int* __restrict__ row_start,
                            int* __restrict__ cursor, int n) {
    __shared__ int buf[1024];
    int tid = threadIdx.x;
    int carry = 0;
    for (int base = 0; base < n; base += 1024) {
        int i = base + tid;
        int v = (i < n) ? deg[i] : 0;
        buf[tid] = v;
        __syncthreads();
        for (int offd = 1; offd < 1024; offd <<= 1) {
            int t = (tid >= offd) ? buf[tid - offd] : 0;
            __syncthreads();
            buf[tid] += t;
            __syncthreads();
        }
        int incl = buf[tid];
        int total = buf[1023];
        if (i < n) {
            int ex = carry + incl - v;
            row_start[i] = ex;
            cursor[i] = ex;
        }
        carry += total;
        __syncthreads();
    }
    if (tid == 0) row_start[n] = carry;
}

__global__ void fill_kernel(const int* __restrict__ src, const int* __restrict__ dst,
                            int* __restrict__ cursor, int* __restrict__ csr_src, int E) {
    int e = blockIdx.x * blockDim.x + threadIdx.x;
    if (e < E) {
        int d = dst[e];
        int p = atomicAdd(&cursor[d], 1);
        csr_src[p] = src[e];
    }
}

// ---------------- fp32 tiled GEMM: C[M,N] = A[M,K] @ B[K,N] ----------------
// BM=64, BN=64, BK=16, 256 threads, 4x4 microtile per thread.

#define BM 64
#define BN 64
#define BK 16

__global__ __launch_bounds__(256) void sgemm_kernel(const float* __restrict__ A,
                                                    const float* __restrict__ B,
                                                    float* __restrict__ C,
                                                    int M, int N, int K) {
    __shared__ float As[BK][BM];  // transposed: As[k][m]
    __shared__ float Bs[BK][BN];

    int tid = threadIdx.x;
    int m_base = blockIdx.x * BM;
    int n_base = blockIdx.y * BN;
    int tx = tid & 15;        // 0..15 -> cols
    int ty = tid >> 4;        // 0..15 -> rows

    // global load indices
    int a_row = tid >> 2;            // 0..63
    int a_kc  = (tid & 3) << 2;      // 0,4,8,12
    int b_row = tid >> 4;            // 0..15
    int b_nc  = (tid & 15) << 2;     // 0..60

    int a_grow = m_base + a_row;
    if (a_grow >= M) a_grow = M - 1;  // clamp (harmless duplicate load)
    const float* Aptr = A + (size_t)a_grow * K + a_kc;
    const float* Bptr = B + (size_t)b_row * N + n_base + b_nc;

    float c[4][4];
#pragma unroll
    for (int i = 0; i < 4; ++i)
#pragma unroll
        for (int j = 0; j < 4; ++j) c[i][j] = 0.0f;

    for (int kb = 0; kb < K; kb += BK) {
        float4 av = *(const float4*)(Aptr + kb);
        float4 bv = *(const float4*)(Bptr + (size_t)kb * N);
        As[a_kc + 0][a_row] = av.x;
        As[a_kc + 1][a_row] = av.y;
        As[a_kc + 2][a_row] = av.z;
        As[a_kc + 3][a_row] = av.w;
        *(float4*)&Bs[b_row][b_nc] = bv;
        __syncthreads();
#pragma unroll
        for (int k = 0; k < BK; ++k) {
            const float4 a = *(const float4*)&As[k][ty << 2];
            const float4 b = *(const float4*)&Bs[k][tx << 2];
            float aa[4] = {a.x, a.y, a.z, a.w};
            float bb[4] = {b.x, b.y, b.z, b.w};
#pragma unroll
            for (int i = 0; i < 4; ++i)
#pragma unroll
                for (int j = 0; j < 4; ++j) c[i][j] += aa[i] * bb[j];
        }
        __syncthreads();
    }

#pragma unroll
    for (int i = 0; i < 4; ++i) {
        int row = m_base + (ty << 2) + i;
        if (row < M) {
            float4 v;
            v.x = c[i][0]; v.y = c[i][1]; v.z = c[i][2]; v.w = c[i][3];
            *(float4*)(C + (size_t)row * N + n_base + (tx << 2)) = v;
        }
    }
}

// ---------------- aggregation + bias + gelu ----------------
// One wave (64 lanes) per node. F=256: float4/lane. F=128: float2/lane.

__global__ __launch_bounds__(256) void agg_gelu_256(const float* __restrict__ h,
                                                    const float* __restrict__ dis,
                                                    const int* __restrict__ row_start,
                                                    const int* __restrict__ csr_src,
                                                    const float* __restrict__ bias,
                                                    float* __restrict__ out, int n) {
    int wid = (blockIdx.x * 256 + threadIdx.x) >> 6;
    int lane = threadIdx.x & 63;
    if (wid >= n) return;
    float di = dis[wid];
    int c0 = lane << 2;
    float4 acc = *(const float4*)(h + (size_t)wid * 256 + c0);  // self loop: weight di
    acc.x *= di; acc.y *= di; acc.z *= di; acc.w *= di;
    int e = row_start[wid], e_end = row_start[wid + 1];
    for (; e + 1 < e_end; e += 2) {
        int j0 = csr_src[e], j1 = csr_src[e + 1];
        float w0 = dis[j0], w1 = dis[j1];
        const float4 h0 = *(const float4*)(h + (size_t)j0 * 256 + c0);
        const float4 h1 = *(const float4*)(h + (size_t)j1 * 256 + c0);
        acc.x += w0 * h0.x + w1 * h1.x;
        acc.y += w0 * h0.y + w1 * h1.y;
        acc.z += w0 * h0.z + w1 * h1.z;
        acc.w += w0 * h0.w + w1 * h1.w;
    }
    if (e < e_end) {
        int j = csr_src[e];
        float w = dis[j];
        const float4 hv = *(const float4*)(h + (size_t)j * 256 + c0);
        acc.x += w * hv.x; acc.y += w * hv.y; acc.z += w * hv.z; acc.w += w * hv.w;
    }
    const float4 bv = *(const float4*)(bias + c0);
    float4 r;
    r.x = gelu_exact(di * acc.x + bv.x);
    r.y = gelu_exact(di * acc.y + bv.y);
    r.z = gelu_exact(di * acc.z + bv.z);
    r.w = gelu_exact(di * acc.w + bv.w);
    *(float4*)(out + (size_t)wid * 256 + c0) = r;
}

__global__ __launch_bounds__(256) void agg_gelu_128(const float* __restrict__ h,
                                                    const float* __restrict__ dis,
                                                    const int* __restrict__ row_start,
                                                    const int* __restrict__ csr_src,
                                                    const float* __restrict__ bias,
                                                    float* __restrict__ out, int n) {
    int wid = (blockIdx.x * 256 + threadIdx.x) >> 6;
    int lane = threadIdx.x & 63;
    if (wid >= n) return;
    float di = dis[wid];
    int c0 = lane << 1;
    float2 acc = *(const float2*)(h + (size_t)wid * 128 + c0);
    acc.x *= di; acc.y *= di;
    int e = row_start[wid], e_end = row_start[wid + 1];
    for (; e + 1 < e_end; e += 2) {
        int j0 = csr_src[e], j1 = csr_src[e + 1];
        float w0 = dis[j0], w1 = dis[j1];
        const float2 h0 = *(const float2*)(h + (size_t)j0 * 128 + c0);
        const float2 h1 = *(const float2*)(h + (size_t)j1 * 128 + c0);
        acc.x += w0 * h0.x + w1 * h1.x;
        acc.y += w0 * h0.y + w1 * h1.y;
    }
    if (e < e_end) {
        int j = csr_src[e];
        float w = dis[j];
        const float2 hv = *(const float2*)(h + (size_t)j * 128 + c0);
        acc.x += w * hv.x; acc.y += w * hv.y;
    }
    const float2 bv = *(const float2*)(bias + c0);
    float2 r;
    r.x = gelu_exact(di * acc.x + bv.x);
    r.y = gelu_exact(di * acc.y + bv.y);
    *(float2*)(out + (size_t)wid * 128 + c0) = r;
}

// ---------------- launch ----------------

extern "C" void kernel_launch(void* const* d_in, const int* in_sizes, int n_in,
                              void* d_out, int out_size, void* d_ws, size_t ws_size,
                              hipStream_t stream) {
    const float* node_emb = (const float*)d_in[0];
    const float* W1 = (const float*)d_in[1];
    const float* b1 = (const float*)d_in[2];
    const float* W2 = (const float*)d_in[3];
    const float* b2 = (const float*)d_in[4];
    const int* edge_index = (const int*)d_in[5];

    const int N = in_sizes[0] / EMB;
    const int E = in_sizes[5] / 2;
    const int* src = edge_index;
    const int* dst = edge_index + E;

    char* ws = (char*)d_ws;
    size_t off = 0;
    auto alloc = [&](size_t bytes) -> void* {
        off = (off + 255) & ~(size_t)255;
        void* p = ws + off;
        off += bytes;
        return p;
    };

    int* deg = (int*)alloc((size_t)N * 4);
    int* row_start = (int*)alloc((size_t)(N + 1) * 4);
    int* cursor = (int*)alloc((size_t)N * 4);
    float* dis = (float*)alloc((size_t)N * 4);
    int* csr_src = (int*)alloc((size_t)E * 4);
    float* h1 = (float*)alloc((size_t)N * MID * 4);  // reused for h2
    float* X1 = (float*)alloc((size_t)N * MID * 4);
    float* h2 = h1;

    hipMemsetAsync(deg, 0, (size_t)N * 4, stream);
    deg_kernel<<<(E + 255) / 256, 256, 0, stream>>>(dst, deg, E);
    dis_kernel<<<(N + 255) / 256, 256, 0, stream>>>(deg, dis, N);
    scan_kernel<<<1, 1024, 0, stream>>>(deg, row_start, cursor, N);
    fill_kernel<<<(E + 255) / 256, 256, 0, stream>>>(src, dst, cursor, csr_src, E);

    // layer 1: h1 = X @ W1  [N,256] ; X1 = gelu(agg(h1) + b1)
    sgemm_kernel<<<dim3((N + BM - 1) / BM, MID / BN), 256, 0, stream>>>(
        node_emb, W1, h1, N, MID, EMB);
    agg_gelu_256<<<(N + 3) / 4, 256, 0, stream>>>(h1, dis, row_start, csr_src, b1, X1, N);

    // layer 2: h2 = X1 @ W2 [N,128] ; out = gelu(agg(h2) + b2)
    sgemm_kernel<<<dim3((N + BM - 1) / BM, OUTF / BN), 256, 0, stream>>>(
        X1, W2, h2, N, OUTF, MID);
    agg_gelu_128<<<(N + 3) / 4, 256, 0, stream>>>(h2, dis, row_start, csr_src, b2,
                                                  (float*)d_out, N);
}

// Round 2
// 503.052 us; speedup vs baseline: 1.1717x; 1.1717x over previous
//
#include <hip/hip_runtime.h>
#include <math.h>

#define EMB 256
#define MID 256
#define OUTF 128

__device__ __forceinline__ float gelu_exact(float x) {
    return 0.5f * x * (1.0f + erff(x * 0.70710678118654752f));
}

// ---------------- graph build ----------------

__global__ void deg_kernel(const int* __restrict__ dst, int* __restrict__ deg, int E) {
    int e = blockIdx.x * blockDim.x + threadIdx.x;
    if (e < E) atomicAdd(&deg[dst[e]], 1);
}

__global__ void dis_kernel(const int* __restrict__ deg, float* __restrict__ dis, int n) {
    int i = blockIdx.x * blockDim.x + threadIdx.x;
    if (i < n) dis[i] = rsqrtf((float)(deg[i] + 1));  // +1: self loop
}

// ---- 3-phase exclusive scan of deg -> row_start / cursor ----

__global__ __launch_bounds__(256) void scan_reduce(const int* __restrict__ deg,
                                                   int* __restrict__ partial, int n) {
    __shared__ int s[256];
    int i = blockIdx.x * 256 + threadIdx.x;
    s[threadIdx.x] = (i < n) ? deg[i] : 0;
    __syncthreads();
    for (int o = 128; o > 0; o >>= 1) {
        if (threadIdx.x < o) s[threadIdx.x] += s[threadIdx.x + o];
        __syncthreads();
    }
    if (threadIdx.x == 0) partial[blockIdx.x] = s[0];
}

// nb <= 256: single block turns partial[] into its exclusive prefix
__global__ __launch_bounds__(256) void scan_partials(int* __restrict__ partial, int nb) {
    __shared__ int s[256];
    int tid = threadIdx.x;
    int v = (tid < nb) ? partial[tid] : 0;
    s[tid] = v;
    __syncthreads();
    for (int o = 1; o < 256; o <<= 1) {
        int t = (tid >= o) ? s[tid - o] : 0;
        __syncthreads();
        s[tid] += t;
        __syncthreads();
    }
    if (tid < nb) partial[tid] = s[tid] - v;
}

__global__ __launch_bounds__(256) void scan_final(const int* __restrict__ deg,
                                                  const int* __restrict__ partial,
                                                  int* __restrict__ row_start,
                                                  int* __restrict__ cursor, int n, int E) {
    __shared__ int s[256];
    int tid = threadIdx.x;
    int i = blockIdx.x * 256 + tid;
    int v = (i < n) ? deg[i] : 0;
    s[tid] = v;
    __syncthreads();
    for (int o = 1; o < 256; o <<= 1) {
        int t = (tid >= o) ? s[tid - o] : 0;
        __syncthreads();
        s[tid] += t;
        __syncthreads();
    }
    int ex = s[tid] - v + partial[blockIdx.x];
    if (i < n) {
        row_start[i] = ex;
        cursor[i] = ex;
    }
    if (i == 0) row_start[n] = E;
}

__global__ void fill_kernel(const int* __restrict__ src, const int* __restrict__ dst,
                            int* __restrict__ cursor, int* __restrict__ csr_src, int E) {
    int e = blockIdx.x * blockDim.x + threadIdx.x;
    if (e < E) {
        int d = dst[e];
        int p = atomicAdd(&cursor[d], 1);
        csr_src[p] = src[e];
    }
}

// ---------------- fp32 tiled GEMM: C[M,N] = scale[m] * (A[M,K] @ B[K,N]) -------
// BM=64, BN=64, BK=16, 256 threads, 4x4 microtile per thread.
// scale = dis: stores h'[m] = dis[m] * (A@B)[m], folding the source-side norm.

#define BM 64
#define BN 64
#define BK 16

__global__ __launch_bounds__(256) void sgemm_scaled(const float* __restrict__ A,
                                                    const float* __restrict__ B,
                                                    const float* __restrict__ scale,
                                                    float* __restrict__ C,
                                                    int M, int N, int K) {
    __shared__ float As[BK][BM];  // transposed: As[k][m]
    __shared__ float Bs[BK][BN];

    int tid = threadIdx.x;
    int m_base = blockIdx.x * BM;
    int n_base = blockIdx.y * BN;
    int tx = tid & 15;
    int ty = tid >> 4;

    int a_row = tid >> 2;
    int a_kc  = (tid & 3) << 2;
    int b_row = tid >> 4;
    int b_nc  = (tid & 15) << 2;

    int a_grow = m_base + a_row;
    if (a_grow >= M) a_grow = M - 1;
    const float* Aptr = A + (size_t)a_grow * K + a_kc;
    const float* Bptr = B + (size_t)b_row * N + n_base + b_nc;

    float c[4][4];
#pragma unroll
    for (int i = 0; i < 4; ++i)
#pragma unroll
        for (int j = 0; j < 4; ++j) c[i][j] = 0.0f;

    for (int kb = 0; kb < K; kb += BK) {
        float4 av = *(const float4*)(Aptr + kb);
        float4 bv = *(const float4*)(Bptr + (size_t)kb * N);
        As[a_kc + 0][a_row] = av.x;
        As[a_kc + 1][a_row] = av.y;
        As[a_kc + 2][a_row] = av.z;
        As[a_kc + 3][a_row] = av.w;
        *(float4*)&Bs[b_row][b_nc] = bv;
        __syncthreads();
#pragma unroll
        for (int k = 0; k < BK; ++k) {
            const float4 a = *(const float4*)&As[k][ty << 2];
            const float4 b = *(const float4*)&Bs[k][tx << 2];
            float aa[4] = {a.x, a.y, a.z, a.w};
            float bb[4] = {b.x, b.y, b.z, b.w};
#pragma unroll
            for (int i = 0; i < 4; ++i)
#pragma unroll
                for (int j = 0; j < 4; ++j) c[i][j] += aa[i] * bb[j];
        }
        __syncthreads();
    }

#pragma unroll
    for (int i = 0; i < 4; ++i) {
        int row = m_base + (ty << 2) + i;
        if (row < M) {
            float sc = scale[row];
            float4 v;
            v.x = sc * c[i][0]; v.y = sc * c[i][1];
            v.z = sc * c[i][2]; v.w = sc * c[i][3];
            *(float4*)(C + (size_t)row * N + n_base + (tx << 2)) = v;
        }
    }
}

// ---------------- aggregation + bias + gelu ----------------
// h is pre-scaled by dis[src]. One wave per node; neighbor indices loaded 64 at
// a time coalesced, then __shfl-broadcast; row loads 4-deep pipelined.
// out[i] = gelu(dis[i] * (h'[i] + sum_j h'[j]) + b)

template <int F>  // F = 256 (float4/lane) or 128 (float2/lane)
__global__ __launch_bounds__(256) void agg_gelu(const float* __restrict__ h,
                                                const float* __restrict__ dis,
                                                const int* __restrict__ row_start,
                                                const int* __restrict__ csr_src,
                                                const float* __restrict__ bias,
                                                float* __restrict__ out, int n) {
    constexpr int VEC = F / 64;  // floats per lane
    int wid = (blockIdx.x * 256 + threadIdx.x) >> 6;
    int lane = threadIdx.x & 63;
    if (wid >= n) return;
    int c0 = lane * VEC;
    const float* hb = h + c0;

    float acc[VEC];
    if (VEC == 4) {
        float4 s = *(const float4*)(hb + (size_t)wid * F);  // self loop (pre-scaled)
        acc[0] = s.x; acc[1] = s.y; acc[2] = s.z; acc[3] = s.w;
    } else {
        float2 s = *(const float2*)(hb + (size_t)wid * F);
        acc[0] = s.x; acc[1] = s.y;
    }

    int e0 = row_start[wid], e1 = row_start[wid + 1];
    for (int base = e0; base < e1; base += 64) {
        int m = e1 - base;
        if (m > 64) m = 64;
        int jmine = (lane < m) ? csr_src[base + lane] : 0;
        int t = 0;
        for (; t + 3 < m; t += 4) {
            int j0 = __shfl(jmine, t);
            int j1 = __shfl(jmine, t + 1);
            int j2 = __shfl(jmine, t + 2);
            int j3 = __shfl(jmine, t + 3);
            if (VEC == 4) {
                float4 r0 = *(const float4*)(hb + (size_t)j0 * F);
                float4 r1 = *(const float4*)(hb + (size_t)j1 * F);
                float4 r2 = *(const float4*)(hb + (size_t)j2 * F);
                float4 r3 = *(const float4*)(hb + (size_t)j3 * F);
                acc[0] += (r0.x + r1.x) + (r2.x + r3.x);
                acc[1] += (r0.y + r1.y) + (r2.y + r3.y);
                acc[2] += (r0.z + r1.z) + (r2.z + r3.z);
                acc[3] += (r0.w + r1.w) + (r2.w + r3.w);
            } else {
                float2 r0 = *(const float2*)(hb + (size_t)j0 * F);
                float2 r1 = *(const float2*)(hb + (size_t)j1 * F);
                float2 r2 = *(const float2*)(hb + (size_t)j2 * F);
                float2 r3 = *(const float2*)(hb + (size_t)j3 * F);
                acc[0] += (r0.x + r1.x) + (r2.x + r3.x);
                acc[1] += (r0.y + r1.y) + (r2.y + r3.y);
            }
        }
        for (; t < m; ++t) {
            int j = __shfl(jmine, t);
            if (VEC == 4) {
                float4 r = *(const float4*)(hb + (size_t)j * F);
                acc[0] += r.x; acc[1] += r.y; acc[2] += r.z; acc[3] += r.w;
            } else {
                float2 r = *(const float2*)(hb + (size_t)j * F);
                acc[0] += r.x; acc[1] += r.y;
            }
        }
    }

    float di = dis[wid];
    if (VEC == 4) {
        const float4 bv = *(const float4*)(bias + c0);
        float4 r;
        r.x = gelu_exact(di * acc[0] + bv.x);
        r.y = gelu_exact(di * acc[1] + bv.y);
        r.z = gelu_exact(di * acc[2] + bv.z);
        r.w = gelu_exact(di * acc[3] + bv.w);
        *(float4*)(out + (size_t)wid * F + c0) = r;
    } else {
        const float2 bv = *(const float2*)(bias + c0);
        float2 r;
        r.x = gelu_exact(di * acc[0] + bv.x);
        r.y = gelu_exact(di * acc[1] + bv.y);
        *(float2*)(out + (size_t)wid * F + c0) = r;
    }
}

// ---------------- launch ----------------

extern "C" void kernel_launch(void* const* d_in, const int* in_sizes, int n_in,
                              void* d_out, int out_size, void* d_ws, size_t ws_size,
                              hipStream_t stream) {
    const float* node_emb = (const float*)d_in[0];
    const float* W1 = (const float*)d_in[1];
    const float* b1 = (const float*)d_in[2];
    const float* W2 = (const float*)d_in[3];
    const float* b2 = (const float*)d_in[4];
    const int* edge_index = (const int*)d_in[5];

    const int N = in_sizes[0] / EMB;
    const int E = in_sizes[5] / 2;
    const int* src = edge_index;
    const int* dst = edge_index + E;

    char* ws = (char*)d_ws;
    size_t off = 0;
    auto alloc = [&](size_t bytes) -> void* {
        off = (off + 255) & ~(size_t)255;
        void* p = ws + off;
        off += bytes;
        return p;
    };

    const int nb = (N + 255) / 256;  // 196 <= 256: single-level partial scan OK

    int* deg = (int*)alloc((size_t)N * 4);
    int* row_start = (int*)alloc((size_t)(N + 1) * 4);
    int* cursor = (int*)alloc((size_t)N * 4);
    float* dis = (float*)alloc((size_t)N * 4);
    int* partial = (int*)alloc((size_t)nb * 4);
    int* csr_src = (int*)alloc((size_t)E * 4);
    float* h1 = (float*)alloc((size_t)N * MID * 4);  // reused for h2
    float* X1 = (float*)alloc((size_t)N * MID * 4);
    float* h2 = h1;

    hipMemsetAsync(deg, 0, (size_t)N * 4, stream);
    deg_kernel<<<(E + 255) / 256, 256, 0, stream>>>(dst, deg, E);
    dis_kernel<<<nb, 256, 0, stream>>>(deg, dis, N);
    scan_reduce<<<nb, 256, 0, stream>>>(deg, partial, N);
    scan_partials<<<1, 256, 0, stream>>>(partial, nb);
    scan_final<<<nb, 256, 0, stream>>>(deg, partial, row_start, cursor, N, E);
    fill_kernel<<<(E + 255) / 256, 256, 0, stream>>>(src, dst, cursor, csr_src, E);

    // layer 1: h1 = dis * (X @ W1) ; X1 = gelu(dis * (agg h1) + b1)
    sgemm_scaled<<<dim3((N + BM - 1) / BM, MID / BN), 256, 0, stream>>>(
        node_emb, W1, dis, h1, N, MID, EMB);
    agg_gelu<256><<<(N + 3) / 4, 256, 0, stream>>>(h1, dis, row_start, csr_src, b1, X1, N);

    // layer 2: h2 = dis * (X1 @ W2) ; out = gelu(dis * (agg h2) + b2)
    sgemm_scaled<<<dim3((N + BM - 1) / BM, OUTF / BN), 256, 0, stream>>>(
        X1, W2, dis, h2, N, OUTF, MID);
    agg_gelu<128><<<(N + 3) / 4, 256, 0, stream>>>(h2, dis, row_start, csr_src, b2,
                                                   (float*)d_out, N);
}

// Round 3
// 438.825 us; speedup vs baseline: 1.3432x; 1.1464x over previous
//
#include <hip/hip_runtime.h>
#include <math.h>

#define EMB 256
#define MID 256
#define OUTF 128

__device__ __forceinline__ float gelu_exact(float x) {
    return 0.5f * x * (1.0f + erff(x * 0.70710678118654752f));
}

__device__ __forceinline__ float bf2f(unsigned int u16) {  // low 16 bits = bf16
    union { unsigned int i; float f; } v;
    v.i = u16 << 16;
    return v.f;
}

__device__ __forceinline__ unsigned short f2bf(float f) {  // RNE
    union { float f; unsigned int i; } v;
    v.f = f;
    unsigned int r = v.i + 0x7fff + ((v.i >> 16) & 1);
    return (unsigned short)(r >> 16);
}

// ---------------- graph build ----------------

__global__ void deg_kernel(const int* __restrict__ dst, int* __restrict__ deg, int E) {
    int e = blockIdx.x * blockDim.x + threadIdx.x;
    if (e < E) atomicAdd(&deg[dst[e]], 1);
}

__global__ void dis_kernel(const int* __restrict__ deg, float* __restrict__ dis, int n) {
    int i = blockIdx.x * blockDim.x + threadIdx.x;
    if (i < n) dis[i] = rsqrtf((float)(deg[i] + 1));  // +1: self loop
}

// ---- 3-phase exclusive scan of deg -> row_start / cursor ----

__global__ __launch_bounds__(256) void scan_reduce(const int* __restrict__ deg,
                                                   int* __restrict__ partial, int n) {
    __shared__ int s[256];
    int i = blockIdx.x * 256 + threadIdx.x;
    s[threadIdx.x] = (i < n) ? deg[i] : 0;
    __syncthreads();
    for (int o = 128; o > 0; o >>= 1) {
        if (threadIdx.x < o) s[threadIdx.x] += s[threadIdx.x + o];
        __syncthreads();
    }
    if (threadIdx.x == 0) partial[blockIdx.x] = s[0];
}

__global__ __launch_bounds__(256) void scan_partials(int* __restrict__ partial, int nb) {
    __shared__ int s[256];
    int tid = threadIdx.x;
    int v = (tid < nb) ? partial[tid] : 0;
    s[tid] = v;
    __syncthreads();
    for (int o = 1; o < 256; o <<= 1) {
        int t = (tid >= o) ? s[tid - o] : 0;
        __syncthreads();
        s[tid] += t;
        __syncthreads();
    }
    if (tid < nb) partial[tid] = s[tid] - v;
}

__global__ __launch_bounds__(256) void scan_final(const int* __restrict__ deg,
                                                  const int* __restrict__ partial,
                                                  int* __restrict__ row_start,
                                                  int* __restrict__ cursor, int n, int E) {
    __shared__ int s[256];
    int tid = threadIdx.x;
    int i = blockIdx.x * 256 + tid;
    int v = (i < n) ? deg[i] : 0;
    s[tid] = v;
    __syncthreads();
    for (int o = 1; o < 256; o <<= 1) {
        int t = (tid >= o) ? s[tid - o] : 0;
        __syncthreads();
        s[tid] += t;
        __syncthreads();
    }
    int ex = s[tid] - v + partial[blockIdx.x];
    if (i < n) {
        row_start[i] = ex;
        cursor[i] = ex;
    }
    if (i == 0) row_start[n] = E;
}

__global__ void fill_kernel(const int* __restrict__ src, const int* __restrict__ dst,
                            int* __restrict__ cursor, int* __restrict__ csr_src, int E) {
    int e = blockIdx.x * blockDim.x + threadIdx.x;
    if (e < E) {
        int d = dst[e];
        int p = atomicAdd(&cursor[d], 1);
        csr_src[p] = src[e];
    }
}

// ---------------- fp32 tiled GEMM: C_bf16[M,N] = scale[m] * (A[M,K] @ B[K,N]) ----
// BM=64, BN=64, BK=16, 256 threads, 4x4 microtile. Output rounded to bf16.

#define BM 64
#define BN 64
#define BK 16

__global__ __launch_bounds__(256) void sgemm_scaled_bf(const float* __restrict__ A,
                                                       const float* __restrict__ B,
                                                       const float* __restrict__ scale,
                                                       unsigned short* __restrict__ C,
                                                       int M, int N, int K) {
    __shared__ float As[BK][BM];  // transposed: As[k][m]
    __shared__ float Bs[BK][BN];

    int tid = threadIdx.x;
    int m_base = blockIdx.x * BM;
    int n_base = blockIdx.y * BN;
    int tx = tid & 15;
    int ty = tid >> 4;

    int a_row = tid >> 2;
    int a_kc  = (tid & 3) << 2;
    int b_row = tid >> 4;
    int b_nc  = (tid & 15) << 2;

    int a_grow = m_base + a_row;
    if (a_grow >= M) a_grow = M - 1;
    const float* Aptr = A + (size_t)a_grow * K + a_kc;
    const float* Bptr = B + (size_t)b_row * N + n_base + b_nc;

    float c[4][4];
#pragma unroll
    for (int i = 0; i < 4; ++i)
#pragma unroll
        for (int j = 0; j < 4; ++j) c[i][j] = 0.0f;

    for (int kb = 0; kb < K; kb += BK) {
        float4 av = *(const float4*)(Aptr + kb);
        float4 bv = *(const float4*)(Bptr + (size_t)kb * N);
        As[a_kc + 0][a_row] = av.x;
        As[a_kc + 1][a_row] = av.y;
        As[a_kc + 2][a_row] = av.z;
        As[a_kc + 3][a_row] = av.w;
        *(float4*)&Bs[b_row][b_nc] = bv;
        __syncthreads();
#pragma unroll
        for (int k = 0; k < BK; ++k) {
            const float4 a = *(const float4*)&As[k][ty << 2];
            const float4 b = *(const float4*)&Bs[k][tx << 2];
            float aa[4] = {a.x, a.y, a.z, a.w};
            float bb[4] = {b.x, b.y, b.z, b.w};
#pragma unroll
            for (int i = 0; i < 4; ++i)
#pragma unroll
                for (int j = 0; j < 4; ++j) c[i][j] += aa[i] * bb[j];
        }
        __syncthreads();
    }

#pragma unroll
    for (int i = 0; i < 4; ++i) {
        int row = m_base + (ty << 2) + i;
        if (row < M) {
            float sc = scale[row];
            uint2 pk;
            pk.x = (unsigned int)f2bf(sc * c[i][0]) | ((unsigned int)f2bf(sc * c[i][1]) << 16);
            pk.y = (unsigned int)f2bf(sc * c[i][2]) | ((unsigned int)f2bf(sc * c[i][3]) << 16);
            *(uint2*)(C + (size_t)row * N + n_base + (tx << 2)) = pk;
        }
    }
}

// ---------------- aggregation + bias + gelu (bf16 h-table) ----------------
// h is bf16, pre-scaled by dis[src]. One wave per node; indices coalesced +
// shfl-broadcast; 8-deep row-load unroll; fp32 accumulate.
// out[i] = gelu(dis[i] * (h'[i] + sum_j h'[j]) + b)   (fp32 out)

template <int F>  // 256: uint2/lane (4 bf16); 128: uint/lane (2 bf16)
__global__ __launch_bounds__(256) void agg_gelu_bf(const unsigned short* __restrict__ h,
                                                   const float* __restrict__ dis,
                                                   const int* __restrict__ row_start,
                                                   const int* __restrict__ csr_src,
                                                   const float* __restrict__ bias,
                                                   float* __restrict__ out, int n) {
    constexpr int VEC = F / 64;  // bf16 elems per lane
    int wid = (blockIdx.x * 256 + threadIdx.x) >> 6;
    int lane = threadIdx.x & 63;
    if (wid >= n) return;
    int c0 = lane * VEC;
    const unsigned short* hb = h + c0;

    float acc[VEC];
    if (VEC == 4) {
        uint2 s = *(const uint2*)(hb + (size_t)wid * F);
        acc[0] = bf2f(s.x & 0xffff); acc[1] = bf2f(s.x >> 16);
        acc[2] = bf2f(s.y & 0xffff); acc[3] = bf2f(s.y >> 16);
    } else {
        unsigned int s = *(const unsigned int*)(hb + (size_t)wid * F);
        acc[0] = bf2f(s & 0xffff); acc[1] = bf2f(s >> 16);
    }

    int e0 = row_start[wid], e1 = row_start[wid + 1];
    for (int base = e0; base < e1; base += 64) {
        int m = e1 - base;
        if (m > 64) m = 64;
        int jmine = (lane < m) ? csr_src[base + lane] : 0;
        int t = 0;
        for (; t + 7 < m; t += 8) {
            int j[8];
#pragma unroll
            for (int u = 0; u < 8; ++u) j[u] = __shfl(jmine, t + u);
            if (VEC == 4) {
                uint2 r[8];
#pragma unroll
                for (int u = 0; u < 8; ++u) r[u] = *(const uint2*)(hb + (size_t)j[u] * F);
#pragma unroll
                for (int u = 0; u < 8; ++u) {
                    acc[0] += bf2f(r[u].x & 0xffff);
                    acc[1] += bf2f(r[u].x >> 16);
                    acc[2] += bf2f(r[u].y & 0xffff);
                    acc[3] += bf2f(r[u].y >> 16);
                }
            } else {
                unsigned int r[8];
#pragma unroll
                for (int u = 0; u < 8; ++u) r[u] = *(const unsigned int*)(hb + (size_t)j[u] * F);
#pragma unroll
                for (int u = 0; u < 8; ++u) {
                    acc[0] += bf2f(r[u] & 0xffff);
                    acc[1] += bf2f(r[u] >> 16);
                }
            }
        }
        for (; t < m; ++t) {
            int jj = __shfl(jmine, t);
            if (VEC == 4) {
                uint2 r = *(const uint2*)(hb + (size_t)jj * F);
                acc[0] += bf2f(r.x & 0xffff); acc[1] += bf2f(r.x >> 16);
                acc[2] += bf2f(r.y & 0xffff); acc[3] += bf2f(r.y >> 16);
            } else {
                unsigned int r = *(const unsigned int*)(hb + (size_t)jj * F);
                acc[0] += bf2f(r & 0xffff); acc[1] += bf2f(r >> 16);
            }
        }
    }

    float di = dis[wid];
    if (VEC == 4) {
        const float4 bv = *(const float4*)(bias + c0);
        float4 r;
        r.x = gelu_exact(di * acc[0] + bv.x);
        r.y = gelu_exact(di * acc[1] + bv.y);
        r.z = gelu_exact(di * acc[2] + bv.z);
        r.w = gelu_exact(di * acc[3] + bv.w);
        *(float4*)(out + (size_t)wid * F + c0) = r;
    } else {
        const float2 bv = *(const float2*)(bias + c0);
        float2 r;
        r.x = gelu_exact(di * acc[0] + bv.x);
        r.y = gelu_exact(di * acc[1] + bv.y);
        *(float2*)(out + (size_t)wid * F + c0) = r;
    }
}

// ---------------- launch ----------------

extern "C" void kernel_launch(void* const* d_in, const int* in_sizes, int n_in,
                              void* d_out, int out_size, void* d_ws, size_t ws_size,
                              hipStream_t stream) {
    const float* node_emb = (const float*)d_in[0];
    const float* W1 = (const float*)d_in[1];
    const float* b1 = (const float*)d_in[2];
    const float* W2 = (const float*)d_in[3];
    const float* b2 = (const float*)d_in[4];
    const int* edge_index = (const int*)d_in[5];

    const int N = in_sizes[0] / EMB;
    const int E = in_sizes[5] / 2;
    const int* src = edge_index;
    const int* dst = edge_index + E;

    char* ws = (char*)d_ws;
    size_t off = 0;
    auto alloc = [&](size_t bytes) -> void* {
        off = (off + 255) & ~(size_t)255;
        void* p = ws + off;
        off += bytes;
        return p;
    };

    const int nb = (N + 255) / 256;  // 196 <= 256: single-level partial scan OK

    int* deg = (int*)alloc((size_t)N * 4);
    int* row_start = (int*)alloc((size_t)(N + 1) * 4);
    int* cursor = (int*)alloc((size_t)N * 4);
    float* dis = (float*)alloc((size_t)N * 4);
    int* partial = (int*)alloc((size_t)nb * 4);
    int* csr_src = (int*)alloc((size_t)E * 4);
    unsigned short* h1 = (unsigned short*)alloc((size_t)N * MID * 2);  // bf16; reused as h2
    float* X1 = (float*)alloc((size_t)N * MID * 4);
    unsigned short* h2 = h1;

    hipMemsetAsync(deg, 0, (size_t)N * 4, stream);
    deg_kernel<<<(E + 255) / 256, 256, 0, stream>>>(dst, deg, E);
    dis_kernel<<<nb, 256, 0, stream>>>(deg, dis, N);
    scan_reduce<<<nb, 256, 0, stream>>>(deg, partial, N);
    scan_partials<<<1, 256, 0, stream>>>(partial, nb);
    scan_final<<<nb, 256, 0, stream>>>(deg, partial, row_start, cursor, N, E);
    fill_kernel<<<(E + 255) / 256, 256, 0, stream>>>(src, dst, cursor, csr_src, E);

    // layer 1: h1 = bf16(dis * (X @ W1)) ; X1 = gelu(dis * (agg h1) + b1)
    sgemm_scaled_bf<<<dim3((N + BM - 1) / BM, MID / BN), 256, 0, stream>>>(
        node_emb, W1, dis, h1, N, MID, EMB);
    agg_gelu_bf<256><<<(N + 3) / 4, 256, 0, stream>>>(h1, dis, row_start, csr_src, b1, X1, N);

    // layer 2: h2 = bf16(dis * (X1 @ W2)) ; out = gelu(dis * (agg h2) + b2)
    sgemm_scaled_bf<<<dim3((N + BM - 1) / BM, OUTF / BN), 256, 0, stream>>>(
        X1, W2, dis, h2, N, OUTF, MID);
    agg_gelu_bf<128><<<(N + 3) / 4, 256, 0, stream>>>(h2, dis, row_start, csr_src, b2,
                                                      (float*)d_out, N);
}

// Round 4
// 329.900 us; speedup vs baseline: 1.7866x; 1.3302x over previous
//
#include <hip/hip_runtime.h>
#include <math.h>

#define EMB 256
#define MID 256
#define OUTF 128
#define KDIM 256  // inner dim for both layers
#define LDK 40    // padded LDS row stride (ushorts) for 32-k chunks

using frag_ab = __attribute__((ext_vector_type(8))) short;  // 8 bf16
using frag_cd = __attribute__((ext_vector_type(4))) float;  // 4 fp32

__device__ __forceinline__ float gelu_exact(float x) {
    return 0.5f * x * (1.0f + erff(x * 0.70710678118654752f));
}

__device__ __forceinline__ float bf2f(unsigned int u16) {
    union { unsigned int i; float f; } v;
    v.i = u16 << 16;
    return v.f;
}

__device__ __forceinline__ unsigned short f2bf(float f) {  // RNE
    union { float f; unsigned int i; } v;
    v.f = f;
    unsigned int r = v.i + 0x7fff + ((v.i >> 16) & 1);
    return (unsigned short)(r >> 16);
}

// ---------------- graph build ----------------

__global__ void deg_kernel(const int* __restrict__ dst, int* __restrict__ deg, int E) {
    int e = blockIdx.x * blockDim.x + threadIdx.x;
    if (e < E) atomicAdd(&deg[dst[e]], 1);
}

__global__ void dis_kernel(const int* __restrict__ deg, float* __restrict__ dis, int n) {
    int i = blockIdx.x * blockDim.x + threadIdx.x;
    if (i < n) dis[i] = rsqrtf((float)(deg[i] + 1));  // +1: self loop
}

__global__ __launch_bounds__(256) void scan_reduce(const int* __restrict__ deg,
                                                   int* __restrict__ partial, int n) {
    __shared__ int s[256];
    int i = blockIdx.x * 256 + threadIdx.x;
    s[threadIdx.x] = (i < n) ? deg[i] : 0;
    __syncthreads();
    for (int o = 128; o > 0; o >>= 1) {
        if (threadIdx.x < o) s[threadIdx.x] += s[threadIdx.x + o];
        __syncthreads();
    }
    if (threadIdx.x == 0) partial[blockIdx.x] = s[0];
}

__global__ __launch_bounds__(256) void scan_partials(int* __restrict__ partial, int nb) {
    __shared__ int s[256];
    int tid = threadIdx.x;
    int v = (tid < nb) ? partial[tid] : 0;
    s[tid] = v;
    __syncthreads();
    for (int o = 1; o < 256; o <<= 1) {
        int t = (tid >= o) ? s[tid - o] : 0;
        __syncthreads();
        s[tid] += t;
        __syncthreads();
    }
    if (tid < nb) partial[tid] = s[tid] - v;
}

__global__ __launch_bounds__(256) void scan_final(const int* __restrict__ deg,
                                                  const int* __restrict__ partial,
                                                  int* __restrict__ row_start,
                                                  int* __restrict__ cursor, int n, int E) {
    __shared__ int s[256];
    int tid = threadIdx.x;
    int i = blockIdx.x * 256 + tid;
    int v = (i < n) ? deg[i] : 0;
    s[tid] = v;
    __syncthreads();
    for (int o = 1; o < 256; o <<= 1) {
        int t = (tid >= o) ? s[tid - o] : 0;
        __syncthreads();
        s[tid] += t;
        __syncthreads();
    }
    int ex = s[tid] - v + partial[blockIdx.x];
    if (i < n) {
        row_start[i] = ex;
        cursor[i] = ex;
    }
    if (i == 0) row_start[n] = E;
}

__global__ void fill_kernel(const int* __restrict__ src, const int* __restrict__ dst,
                            int* __restrict__ cursor, int* __restrict__ csr_src, int E) {
    int e = blockIdx.x * blockDim.x + threadIdx.x;
    if (e < E) {
        int d = dst[e];
        int p = atomicAdd(&cursor[d], 1);
        csr_src[p] = src[e];
    }
}

// W [K][Nw] fp32 -> Wt [Nw][K] bf16 (transposed, so B frags are contiguous in k)
__global__ void wt_kernel(const float* __restrict__ W, unsigned short* __restrict__ Wt,
                          int K, int Nw) {
    int id = blockIdx.x * blockDim.x + threadIdx.x;
    if (id < K * Nw) {
        int k = id / Nw, n = id % Nw;
        Wt[(size_t)n * K + k] = f2bf(W[(size_t)k * Nw + n]);
    }
}

// ---------------- MFMA bf16 GEMM: C_bf16[M,Ntot] = dis[m] * (A[M,256] @ Wt^T) ----
// 128x128 tile, 256 threads = 4 waves (2x2, 64x64 each), K-chunks of 32.
// A_FP32: A is fp32 (converted in staging); else A is bf16.

template <bool A_FP32>
__global__ __launch_bounds__(256) void mfma_gemm(const void* __restrict__ Av,
                                                 const unsigned short* __restrict__ Wt,
                                                 const float* __restrict__ dis,
                                                 unsigned short* __restrict__ C,
                                                 int M, int Ntot) {
    __shared__ __align__(16) unsigned short As[128 * LDK];
    __shared__ __align__(16) unsigned short Bs[128 * LDK];

    const int tid = threadIdx.x;
    const int m0 = blockIdx.x * 128;
    const int n0 = blockIdx.y * 128;
    const int wave = tid >> 6, lane = tid & 63;
    const int wrow = (wave >> 1) * 64, wcol = (wave & 1) * 64;
    const int q = lane >> 4, r = lane & 15;

    frag_cd acc[4][4] = {};

    const int qb = tid & 3;   // k8 = qb*8 (16B chunk of k)
    const int nb = tid >> 2;  // 0..63

    for (int ks = 0; ks < KDIM; ks += 32) {
        if (A_FP32) {
            const float* A = (const float*)Av;
            int qa = tid & 7;   // k4 = qa*4
            int ra = tid >> 3;  // 0..31
#pragma unroll
            for (int rr = 0; rr < 4; ++rr) {
                int row = ra + rr * 32;
                int grow = m0 + row;
                if (grow >= M) grow = M - 1;
                float4 v = *(const float4*)(A + (size_t)grow * KDIM + ks + qa * 4);
                ushort4 w;
                w.x = f2bf(v.x); w.y = f2bf(v.y); w.z = f2bf(v.z); w.w = f2bf(v.w);
                *(ushort4*)&As[row * LDK + qa * 4] = w;
            }
        } else {
            const unsigned short* A = (const unsigned short*)Av;
#pragma unroll
            for (int rr = 0; rr < 2; ++rr) {
                int row = nb + rr * 64;
                int grow = m0 + row;
                if (grow >= M) grow = M - 1;
                uint4 v = *(const uint4*)(A + (size_t)grow * KDIM + ks + qb * 8);
                *(uint4*)&As[row * LDK + qb * 8] = v;
            }
        }
#pragma unroll
        for (int rr = 0; rr < 2; ++rr) {
            int n = nb + rr * 64;
            uint4 v = *(const uint4*)(Wt + (size_t)(n0 + n) * KDIM + ks + qb * 8);
            *(uint4*)&Bs[n * LDK + qb * 8] = v;
        }
        __syncthreads();

        frag_ab af[4], bfr[4];
#pragma unroll
        for (int i = 0; i < 4; ++i)
            af[i] = *(const frag_ab*)&As[(wrow + i * 16 + r) * LDK + q * 8];
#pragma unroll
        for (int j = 0; j < 4; ++j)
            bfr[j] = *(const frag_ab*)&Bs[(wcol + j * 16 + r) * LDK + q * 8];
#pragma unroll
        for (int i = 0; i < 4; ++i)
#pragma unroll
            for (int j = 0; j < 4; ++j)
                acc[i][j] = __builtin_amdgcn_mfma_f32_16x16x32_bf16(af[i], bfr[j],
                                                                    acc[i][j], 0, 0, 0);
        __syncthreads();
    }

    // epilogue: D[row = m0+wrow+i*16+q*4+g][col = n0+wcol+j*16+r]
    float disv[4][4];
#pragma unroll
    for (int i = 0; i < 4; ++i)
#pragma unroll
        for (int g = 0; g < 4; ++g) {
            int row = m0 + wrow + i * 16 + q * 4 + g;
            disv[i][g] = (row < M) ? dis[row] : 0.0f;
        }
#pragma unroll
    for (int i = 0; i < 4; ++i)
#pragma unroll
        for (int g = 0; g < 4; ++g) {
            int row = m0 + wrow + i * 16 + q * 4 + g;
            if (row < M) {
                float sc = disv[i][g];
#pragma unroll
                for (int j = 0; j < 4; ++j) {
                    int col = n0 + wcol + j * 16 + r;
                    C[(size_t)row * Ntot + col] = f2bf(acc[i][j][g] * sc);
                }
            }
        }
}

// ---------------- aggregation + bias + gelu (bf16 h-table) ----------------
// out[i] = gelu(dis[i] * (h'[i] + sum_j h'[j]) + b);  OUT_BF: bf16 out else fp32.

template <int F, bool OUT_BF>
__global__ __launch_bounds__(256) void agg_gelu_bf(const unsigned short* __restrict__ h,
                                                   const float* __restrict__ dis,
                                                   const int* __restrict__ row_start,
                                                   const int* __restrict__ csr_src,
                                                   const float* __restrict__ bias,
                                                   void* __restrict__ out, int n) {
    constexpr int VEC = F / 64;
    int wid = (blockIdx.x * 256 + threadIdx.x) >> 6;
    int lane = threadIdx.x & 63;
    if (wid >= n) return;
    int c0 = lane * VEC;
    const unsigned short* hb = h + c0;

    float acc[VEC];
    if (VEC == 4) {
        uint2 s = *(const uint2*)(hb + (size_t)wid * F);
        acc[0] = bf2f(s.x & 0xffff); acc[1] = bf2f(s.x >> 16);
        acc[2] = bf2f(s.y & 0xffff); acc[3] = bf2f(s.y >> 16);
    } else {
        unsigned int s = *(const unsigned int*)(hb + (size_t)wid * F);
        acc[0] = bf2f(s & 0xffff); acc[1] = bf2f(s >> 16);
    }

    int e0 = row_start[wid], e1 = row_start[wid + 1];
    for (int base = e0; base < e1; base += 64) {
        int m = e1 - base;
        if (m > 64) m = 64;
        int jmine = (lane < m) ? csr_src[base + lane] : 0;
        int t = 0;
        for (; t + 7 < m; t += 8) {
            int j[8];
#pragma unroll
            for (int u = 0; u < 8; ++u) j[u] = __shfl(jmine, t + u);
            if (VEC == 4) {
                uint2 rr[8];
#pragma unroll
                for (int u = 0; u < 8; ++u) rr[u] = *(const uint2*)(hb + (size_t)j[u] * F);
#pragma unroll
                for (int u = 0; u < 8; ++u) {
                    acc[0] += bf2f(rr[u].x & 0xffff);
                    acc[1] += bf2f(rr[u].x >> 16);
                    acc[2] += bf2f(rr[u].y & 0xffff);
                    acc[3] += bf2f(rr[u].y >> 16);
                }
            } else {
                unsigned int rr[8];
#pragma unroll
                for (int u = 0; u < 8; ++u) rr[u] = *(const unsigned int*)(hb + (size_t)j[u] * F);
#pragma unroll
                for (int u = 0; u < 8; ++u) {
                    acc[0] += bf2f(rr[u] & 0xffff);
                    acc[1] += bf2f(rr[u] >> 16);
                }
            }
        }
        for (; t < m; ++t) {
            int jj = __shfl(jmine, t);
            if (VEC == 4) {
                uint2 rr = *(const uint2*)(hb + (size_t)jj * F);
                acc[0] += bf2f(rr.x & 0xffff); acc[1] += bf2f(rr.x >> 16);
                acc[2] += bf2f(rr.y & 0xffff); acc[3] += bf2f(rr.y >> 16);
            } else {
                unsigned int rr = *(const unsigned int*)(hb + (size_t)jj * F);
                acc[0] += bf2f(rr & 0xffff); acc[1] += bf2f(rr >> 16);
            }
        }
    }

    float di = dis[wid];
    float res[VEC];
#pragma unroll
    for (int u = 0; u < VEC; ++u) res[u] = gelu_exact(di * acc[u] + bias[c0 + u]);

    if (OUT_BF) {
        unsigned short* ob = (unsigned short*)out + (size_t)wid * F + c0;
        if (VEC == 4) {
            uint2 pk;
            pk.x = (unsigned int)f2bf(res[0]) | ((unsigned int)f2bf(res[1]) << 16);
            pk.y = (unsigned int)f2bf(res[2]) | ((unsigned int)f2bf(res[3]) << 16);
            *(uint2*)ob = pk;
        } else {
            unsigned int pk = (unsigned int)f2bf(res[0]) | ((unsigned int)f2bf(res[1]) << 16);
            *(unsigned int*)ob = pk;
        }
    } else {
        float* ob = (float*)out + (size_t)wid * F + c0;
        if (VEC == 4) {
            float4 rv; rv.x = res[0]; rv.y = res[1]; rv.z = res[2]; rv.w = res[3];
            *(float4*)ob = rv;
        } else {
            float2 rv; rv.x = res[0]; rv.y = res[1];
            *(float2*)ob = rv;
        }
    }
}

// ---------------- launch ----------------

extern "C" void kernel_launch(void* const* d_in, const int* in_sizes, int n_in,
                              void* d_out, int out_size, void* d_ws, size_t ws_size,
                              hipStream_t stream) {
    const float* node_emb = (const float*)d_in[0];
    const float* W1 = (const float*)d_in[1];
    const float* b1 = (const float*)d_in[2];
    const float* W2 = (const float*)d_in[3];
    const float* b2 = (const float*)d_in[4];
    const int* edge_index = (const int*)d_in[5];

    const int N = in_sizes[0] / EMB;
    const int E = in_sizes[5] / 2;
    const int* src = edge_index;
    const int* dst = edge_index + E;

    char* ws = (char*)d_ws;
    size_t off = 0;
    auto alloc = [&](size_t bytes) -> void* {
        off = (off + 255) & ~(size_t)255;
        void* p = ws + off;
        off += bytes;
        return p;
    };

    const int nb = (N + 255) / 256;

    int* deg = (int*)alloc((size_t)N * 4);
    int* row_start = (int*)alloc((size_t)(N + 1) * 4);
    int* cursor = (int*)alloc((size_t)N * 4);
    float* dis = (float*)alloc((size_t)N * 4);
    int* partial = (int*)alloc((size_t)nb * 4);
    int* csr_src = (int*)alloc((size_t)E * 4);
    unsigned short* W1t = (unsigned short*)alloc((size_t)EMB * MID * 2);   // [N=256][K=256]
    unsigned short* W2t = (unsigned short*)alloc((size_t)MID * OUTF * 2);  // [N=128][K=256]
    unsigned short* h1 = (unsigned short*)alloc((size_t)N * MID * 2);      // bf16; reused as h2
    unsigned short* X1 = (unsigned short*)alloc((size_t)N * MID * 2);      // bf16
    unsigned short* h2 = h1;

    hipMemsetAsync(deg, 0, (size_t)N * 4, stream);
    deg_kernel<<<(E + 255) / 256, 256, 0, stream>>>(dst, deg, E);
    dis_kernel<<<nb, 256, 0, stream>>>(deg, dis, N);
    scan_reduce<<<nb, 256, 0, stream>>>(deg, partial, N);
    scan_partials<<<1, 256, 0, stream>>>(partial, nb);
    scan_final<<<nb, 256, 0, stream>>>(deg, partial, row_start, cursor, N, E);
    fill_kernel<<<(E + 255) / 256, 256, 0, stream>>>(src, dst, cursor, csr_src, E);
    wt_kernel<<<(EMB * MID + 255) / 256, 256, 0, stream>>>(W1, W1t, EMB, MID);
    wt_kernel<<<(MID * OUTF + 255) / 256, 256, 0, stream>>>(W2, W2t, MID, OUTF);

    const int gm = (N + 127) / 128;

    // layer 1: h1 = bf16(dis * (X @ W1)) via MFMA ; X1 = bf16(gelu(dis*agg(h1)+b1))
    mfma_gemm<true><<<dim3(gm, MID / 128), 256, 0, stream>>>(node_emb, W1t, dis, h1, N, MID);
    agg_gelu_bf<256, true><<<(N + 3) / 4, 256, 0, stream>>>(h1, dis, row_start, csr_src,
                                                            b1, X1, N);

    // layer 2: h2 = bf16(dis * (X1 @ W2)) via MFMA ; out = gelu(dis*agg(h2)+b2) fp32
    mfma_gemm<false><<<dim3(gm, OUTF / 128), 256, 0, stream>>>(X1, W2t, dis, h2, N, OUTF);
    agg_gelu_bf<128, false><<<(N + 3) / 4, 256, 0, stream>>>(h2, dis, row_start, csr_src,
                                                             b2, d_out, N);
}

// Round 5
// 323.228 us; speedup vs baseline: 1.8235x; 1.0206x over previous
//
#include <hip/hip_runtime.h>
#include <math.h>

#define EMB 256
#define MID 256
#define OUTF 128
#define KDIM 256  // inner dim for both layers
#define LDK 40    // padded LDS row stride (ushorts) for 32-k chunks

using frag_ab = __attribute__((ext_vector_type(8))) short;  // 8 bf16
using frag_cd = __attribute__((ext_vector_type(4))) float;  // 4 fp32
typedef float f32x2 __attribute__((ext_vector_type(2)));

__device__ __forceinline__ float gelu_exact(float x) {
    return 0.5f * x * (1.0f + erff(x * 0.70710678118654752f));
}

__device__ __forceinline__ unsigned short f2bf(float f) {  // RNE
    union { float f; unsigned int i; } v;
    v.f = f;
    unsigned int r = v.i + 0x7fff + ((v.i >> 16) & 1);
    return (unsigned short)(r >> 16);
}

// unpack one uint (2 bf16) -> packed float2 {low, high}
__device__ __forceinline__ f32x2 bfpair(unsigned int u) {
    union { unsigned int i; float f; } a, b;
    a.i = u << 16;
    b.i = u & 0xffff0000u;
    f32x2 r;
    r.x = a.f; r.y = b.f;
    return r;
}

// ---------------- graph build ----------------

__global__ void deg_kernel(const int* __restrict__ dst, int* __restrict__ deg, int E) {
    int e = blockIdx.x * blockDim.x + threadIdx.x;
    if (e < E) atomicAdd(&deg[dst[e]], 1);
}

__global__ __launch_bounds__(256) void scan_reduce(const int* __restrict__ deg,
                                                   int* __restrict__ partial, int n) {
    __shared__ int s[256];
    int i = blockIdx.x * 256 + threadIdx.x;
    s[threadIdx.x] = (i < n) ? deg[i] : 0;
    __syncthreads();
    for (int o = 128; o > 0; o >>= 1) {
        if (threadIdx.x < o) s[threadIdx.x] += s[threadIdx.x + o];
        __syncthreads();
    }
    if (threadIdx.x == 0) partial[blockIdx.x] = s[0];
}

__global__ __launch_bounds__(256) void scan_partials(int* __restrict__ partial, int nb) {
    __shared__ int s[256];
    int tid = threadIdx.x;
    int v = (tid < nb) ? partial[tid] : 0;
    s[tid] = v;
    __syncthreads();
    for (int o = 1; o < 256; o <<= 1) {
        int t = (tid >= o) ? s[tid - o] : 0;
        __syncthreads();
        s[tid] += t;
        __syncthreads();
    }
    if (tid < nb) partial[tid] = s[tid] - v;
}

// also computes dis = rsqrt(deg+1)
__global__ __launch_bounds__(256) void scan_final(const int* __restrict__ deg,
                                                  const int* __restrict__ partial,
                                                  int* __restrict__ row_start,
                                                  int* __restrict__ cursor,
                                                  float* __restrict__ dis, int n, int E) {
    __shared__ int s[256];
    int tid = threadIdx.x;
    int i = blockIdx.x * 256 + tid;
    int v = (i < n) ? deg[i] : 0;
    s[tid] = v;
    __syncthreads();
    for (int o = 1; o < 256; o <<= 1) {
        int t = (tid >= o) ? s[tid - o] : 0;
        __syncthreads();
        s[tid] += t;
        __syncthreads();
    }
    int ex = s[tid] - v + partial[blockIdx.x];
    if (i < n) {
        row_start[i] = ex;
        cursor[i] = ex;
        dis[i] = rsqrtf((float)(v + 1));
    }
    if (i == 0) row_start[n] = E;
}

__global__ void fill_kernel(const int* __restrict__ src, const int* __restrict__ dst,
                            int* __restrict__ cursor, int* __restrict__ csr_src, int E) {
    int e = blockIdx.x * blockDim.x + threadIdx.x;
    if (e < E) {
        int d = dst[e];
        int p = atomicAdd(&cursor[d], 1);
        csr_src[p] = src[e];
    }
}

// both weight transposes in one launch: W [K][Nw] fp32 -> Wt [Nw][K] bf16
__global__ void wt_both(const float* __restrict__ W1, const float* __restrict__ W2,
                        unsigned short* __restrict__ W1t, unsigned short* __restrict__ W2t) {
    int id = blockIdx.x * blockDim.x + threadIdx.x;
    const int t1 = EMB * MID;
    if (id < t1) {
        int k = id >> 8, n = id & 255;  // Nw=256
        W1t[(size_t)n * EMB + k] = f2bf(W1[(size_t)k * MID + n]);
    } else {
        id -= t1;
        if (id < MID * OUTF) {
            int k = id >> 7, n = id & 127;  // Nw=128
            W2t[(size_t)n * MID + k] = f2bf(W2[(size_t)k * OUTF + n]);
        }
    }
}

// ---------------- MFMA bf16 GEMM: C_bf16[M, NT*128] = dis[m]*(A[M,256] @ Wt^T) ----
// M-tile 128, full N in one block (NT = Ntot/128). 256 threads = 4 waves (2x2).

template <bool A_FP32, int NT>
__global__ __launch_bounds__(256, 1) void mfma_gemm(const void* __restrict__ Av,
                                                    const unsigned short* __restrict__ Wt,
                                                    const float* __restrict__ dis,
                                                    unsigned short* __restrict__ C,
                                                    int M) {
    constexpr int Ntot = NT * 128;
    __shared__ __align__(16) unsigned short As[128 * LDK];
    __shared__ __align__(16) unsigned short Bs[NT * 128 * LDK];

    const int tid = threadIdx.x;
    const int m0 = blockIdx.x * 128;
    const int wave = tid >> 6, lane = tid & 63;
    const int wrow = (wave >> 1) * 64, wcol = (wave & 1) * 64;
    const int q = lane >> 4, r = lane & 15;

    frag_cd acc[NT][4][4] = {};

    const int qb = tid & 3;   // 16B k-chunk
    const int nb = tid >> 2;  // 0..63

    for (int ks = 0; ks < KDIM; ks += 32) {
        if (A_FP32) {
            const float* A = (const float*)Av;
            int qa = tid & 7;   // k4 = qa*4
            int ra = tid >> 3;  // 0..31
#pragma unroll
            for (int rr = 0; rr < 4; ++rr) {
                int row = ra + rr * 32;
                int grow = m0 + row;
                if (grow >= M) grow = M - 1;
                float4 v = *(const float4*)(A + (size_t)grow * KDIM + ks + qa * 4);
                ushort4 w;
                w.x = f2bf(v.x); w.y = f2bf(v.y); w.z = f2bf(v.z); w.w = f2bf(v.w);
                *(ushort4*)&As[row * LDK + qa * 4] = w;
            }
        } else {
            const unsigned short* A = (const unsigned short*)Av;
#pragma unroll
            for (int rr = 0; rr < 2; ++rr) {
                int row = nb + rr * 64;
                int grow = m0 + row;
                if (grow >= M) grow = M - 1;
                uint4 v = *(const uint4*)(A + (size_t)grow * KDIM + ks + qb * 8);
                *(uint4*)&As[row * LDK + qb * 8] = v;
            }
        }
#pragma unroll
        for (int rr = 0; rr < 2 * NT; ++rr) {
            int n = nb + rr * 64;
            uint4 v = *(const uint4*)(Wt + (size_t)n * KDIM + ks + qb * 8);
            *(uint4*)&Bs[n * LDK + qb * 8] = v;
        }
        __syncthreads();

        frag_ab af[4];
#pragma unroll
        for (int i = 0; i < 4; ++i)
            af[i] = *(const frag_ab*)&As[(wrow + i * 16 + r) * LDK + q * 8];
#pragma unroll
        for (int nt = 0; nt < NT; ++nt) {
            frag_ab bfr[4];
#pragma unroll
            for (int j = 0; j < 4; ++j)
                bfr[j] = *(const frag_ab*)&Bs[(nt * 128 + wcol + j * 16 + r) * LDK + q * 8];
#pragma unroll
            for (int i = 0; i < 4; ++i)
#pragma unroll
                for (int j = 0; j < 4; ++j)
                    acc[nt][i][j] = __builtin_amdgcn_mfma_f32_16x16x32_bf16(
                        af[i], bfr[j], acc[nt][i][j], 0, 0, 0);
        }
        __syncthreads();
    }

    // epilogue: D[row = m0+wrow+i*16+q*4+g][col = nt*128+wcol+j*16+r]
#pragma unroll
    for (int i = 0; i < 4; ++i)
#pragma unroll
        for (int g = 0; g < 4; ++g) {
            int row = m0 + wrow + i * 16 + q * 4 + g;
            if (row < M) {
                float sc = dis[row];
#pragma unroll
                for (int nt = 0; nt < NT; ++nt)
#pragma unroll
                    for (int j = 0; j < 4; ++j) {
                        int col = nt * 128 + wcol + j * 16 + r;
                        C[(size_t)row * Ntot + col] = f2bf(acc[nt][i][j][g] * sc);
                    }
            }
        }
}

// ---------------- aggregation + bias + gelu (bf16 h-table, zero-row padded) -----
// h has n+1 rows; row n is all zeros (pad target). Indices via readlane -> SGPR,
// loads are saddr-form; depth-8 ping-pong double buffer keeps loads in flight
// under the accumulate VALU. out[i] = gelu(dis[i]*(h'[i]+sum_j h'[j]) + b).

template <int VEC> struct ldt;
template <> struct ldt<4> { using T = uint2; };
template <> struct ldt<2> { using T = unsigned int; };

template <int F, bool OUT_BF>
__global__ __launch_bounds__(256) void agg_gelu2(const unsigned short* __restrict__ h,
                                                 const float* __restrict__ dis,
                                                 const int* __restrict__ row_start,
                                                 const int* __restrict__ csr_src,
                                                 const float* __restrict__ bias,
                                                 void* __restrict__ out, int n) {
    constexpr int VEC = F / 64;
    using LT = typename ldt<VEC>::T;
    int wid = (blockIdx.x * 256 + threadIdx.x) >> 6;
    int lane = threadIdx.x & 63;
    if (wid >= n) return;
    const int c0 = lane * VEC;
    const unsigned short* hb = h + c0;

    f32x2 acc[VEC / 2];
    {
        LT s = *(const LT*)(hb + (size_t)wid * F);  // self loop (pre-scaled by dis)
        if (VEC == 4) {
            uint2 u = *(uint2*)&s;
            acc[0] = bfpair(u.x);
            acc[VEC / 2 - 1] = bfpair(u.y);
        } else {
            acc[0] = bfpair(*(unsigned int*)&s);
        }
    }

    int e0 = row_start[wid], e1 = row_start[wid + 1];
    for (int base = e0; base < e1; base += 64) {
        int rem = e1 - base;
        int m = rem < 64 ? rem : 64;
        int jmine = (lane < m) ? csr_src[base + lane] : n;  // pad -> zero row
        int mp = (m + 7) & ~7;

        LT A[8], B[8];
        auto load8 = [&](LT* buf, int t) {
#pragma unroll
            for (int u = 0; u < 8; ++u) {
                int j = __builtin_amdgcn_readlane(jmine, t + u);
                buf[u] = *(const LT*)(hb + (size_t)j * F);
            }
        };
        auto acc8 = [&](const LT* buf) {
#pragma unroll
            for (int u = 0; u < 8; ++u) {
                if (VEC == 4) {
                    uint2 v = *(uint2*)&buf[u];
                    acc[0] += bfpair(v.x);
                    acc[VEC / 2 - 1] += bfpair(v.y);
                } else {
                    acc[0] += bfpair(*(unsigned int*)&buf[u]);
                }
            }
        };

        load8(A, 0);
        int t = 8;
        for (;;) {
            if (t >= mp) { acc8(A); break; }
            load8(B, t); acc8(A); t += 8;
            if (t >= mp) { acc8(B); break; }
            load8(A, t); acc8(B); t += 8;
        }
    }

    float di = dis[wid];
    float res[VEC];
#pragma unroll
    for (int p = 0; p < VEC / 2; ++p) {
        res[2 * p + 0] = gelu_exact(di * acc[p].x + bias[c0 + 2 * p + 0]);
        res[2 * p + 1] = gelu_exact(di * acc[p].y + bias[c0 + 2 * p + 1]);
    }

    if (OUT_BF) {
        unsigned short* ob = (unsigned short*)out + (size_t)wid * F + c0;
        if (VEC == 4) {
            uint2 pk;
            pk.x = (unsigned int)f2bf(res[0]) | ((unsigned int)f2bf(res[1]) << 16);
            pk.y = (unsigned int)f2bf(res[2]) | ((unsigned int)f2bf(res[3]) << 16);
            *(uint2*)ob = pk;
        } else {
            unsigned int pk = (unsigned int)f2bf(res[0]) | ((unsigned int)f2bf(res[1]) << 16);
            *(unsigned int*)ob = pk;
        }
    } else {
        float* ob = (float*)out + (size_t)wid * F + c0;
        if (VEC == 4) {
            float4 rv; rv.x = res[0]; rv.y = res[1]; rv.z = res[2]; rv.w = res[3];
            *(float4*)ob = rv;
        } else {
            float2 rv; rv.x = res[0]; rv.y = res[1];
            *(float2*)ob = rv;
        }
    }
}

// ---------------- launch ----------------

extern "C" void kernel_launch(void* const* d_in, const int* in_sizes, int n_in,
                              void* d_out, int out_size, void* d_ws, size_t ws_size,
                              hipStream_t stream) {
    const float* node_emb = (const float*)d_in[0];
    const float* W1 = (const float*)d_in[1];
    const float* b1 = (const float*)d_in[2];
    const float* W2 = (const float*)d_in[3];
    const float* b2 = (const float*)d_in[4];
    const int* edge_index = (const int*)d_in[5];

    const int N = in_sizes[0] / EMB;
    const int E = in_sizes[5] / 2;
    const int* src = edge_index;
    const int* dst = edge_index + E;

    char* ws = (char*)d_ws;
    size_t off = 0;
    auto alloc = [&](size_t bytes) -> void* {
        off = (off + 255) & ~(size_t)255;
        void* p = ws + off;
        off += bytes;
        return p;
    };

    const int nb = (N + 255) / 256;  // 196 <= 256

    int* deg = (int*)alloc((size_t)N * 4);
    int* row_start = (int*)alloc((size_t)(N + 1) * 4);
    int* cursor = (int*)alloc((size_t)N * 4);
    float* dis = (float*)alloc((size_t)N * 4);
    int* partial = (int*)alloc((size_t)nb * 4);
    int* csr_src = (int*)alloc((size_t)E * 4);
    unsigned short* W1t = (unsigned short*)alloc((size_t)EMB * MID * 2);   // [256][256]
    unsigned short* W2t = (unsigned short*)alloc((size_t)MID * OUTF * 2);  // [128][256]
    unsigned short* h1 = (unsigned short*)alloc((size_t)(N + 1) * MID * 2);  // +zero row
    unsigned short* X1 = (unsigned short*)alloc((size_t)N * MID * 2);
    unsigned short* h2 = h1;  // reused, row stride 128

    hipMemsetAsync(deg, 0, (size_t)N * 4, stream);
    deg_kernel<<<(E + 255) / 256, 256, 0, stream>>>(dst, deg, E);
    scan_reduce<<<nb, 256, 0, stream>>>(deg, partial, N);
    scan_partials<<<1, 256, 0, stream>>>(partial, nb);
    scan_final<<<nb, 256, 0, stream>>>(deg, partial, row_start, cursor, dis, N, E);
    fill_kernel<<<(E + 255) / 256, 256, 0, stream>>>(src, dst, cursor, csr_src, E);
    wt_both<<<(EMB * MID + MID * OUTF + 255) / 256, 256, 0, stream>>>(W1, W2, W1t, W2t);

    const int gm = (N + 127) / 128;

    // h1 zero row (row N, stride 256): 512 B
    hipMemsetAsync(h1 + (size_t)N * MID, 0, MID * 2, stream);

    // layer 1: h1 = bf16(dis * (X @ W1)), full 256-wide N per block
    mfma_gemm<true, 2><<<gm, 256, 0, stream>>>(node_emb, W1t, dis, h1, N);
    agg_gelu2<256, true><<<(N + 3) / 4, 256, 0, stream>>>(h1, dis, row_start, csr_src,
                                                          b1, X1, N);

    // layer 2: h2 = bf16(dis * (X1 @ W2))
    mfma_gemm<false, 1><<<gm, 256, 0, stream>>>(X1, W2t, dis, h2, N);
    // h2 zero row (row N, stride 128): 256 B — after gemm2 (region held stale h1 data)
    hipMemsetAsync(h2 + (size_t)N * OUTF, 0, OUTF * 2, stream);
    agg_gelu2<128, false><<<(N + 3) / 4, 256, 0, stream>>>(h2, dis, row_start, csr_src,
                                                           b2, d_out, N);
}